// Round 7
// baseline (298.374 us; speedup 1.0000x reference)
//
#include <hip/hip_runtime.h>
#include <math.h>

#define TOKENS    1024
#define IN_W      512
#define BLOCK_H   256
#define OUT_W     512
#define N_EXPERTS 64
#define TOPK      2
#define NSLOTS    (TOKENS * TOPK)
#define LIST_CAP  128     // ne ~ Binom(2048,1/64): mean 32, sigma 5.6
#define T_GRP     12      // tokens per chunk; 4 groups x 12 covers ne <= 48 in one pass
#define NGRP      4       // groups per expert -> 256 blocks = 1/CU
#define XPAD      520     // x row stride (floats); 2080 B, 16B-aligned
#define VPAD      260     // v / psum1 row stride; 1040 B, 16B-aligned
#define P2PAD     516     // psum2 row stride; 2064 B, 16B-aligned

__device__ __forceinline__ void fma4(float4& a, float s, const float4& w) {
    a.x = fmaf(s, w.x, a.x); a.y = fmaf(s, w.y, a.y);
    a.z = fmaf(s, w.z, a.z); a.w = fmaf(s, w.w, a.w);
}

// ---------------------------------------------------------------------------
// Routing + fused compaction (unchanged from round 5).
// ---------------------------------------------------------------------------
__global__ __launch_bounds__(256) void routing_kernel(
    const float* __restrict__ x, const float* __restrict__ noise,
    const float* __restrict__ mixer, const float* __restrict__ noisec,
    float* __restrict__ esc, int* __restrict__ counts, int* __restrict__ lists)
{
    __shared__ float xs[2 * 512];
    __shared__ float pm[2 * 2 * 64];
    __shared__ float pn[2 * 2 * 64];
    const int blk  = blockIdx.x;
    const int tid  = threadIdx.x;
    const int wave = tid >> 6, lane = tid & 63;
    const int tq = wave >> 1;
    const int ih = wave & 1;

    ((float4*)xs)[tid] = ((const float4*)x)[(size_t)blk * 256 + tid];
    __syncthreads();

    float am = 0.f, an = 0.f;
    const float* xp = xs + tq * 512 + ih * 256;
    const float* mp = mixer  + (size_t)(ih * 256) * 64 + lane;
    const float* np = noisec + (size_t)(ih * 256) * 64 + lane;
    #pragma unroll 8
    for (int i = 0; i < 256; ++i) {
        const float xv = xp[i];
        am = fmaf(xv, mp[i * 64], am);
        an = fmaf(xv, np[i * 64], an);
    }
    pm[tq * 128 + ih * 64 + lane] = am;
    pn[tq * 128 + ih * 64 + lane] = an;
    __syncthreads();

    if (tid < 128) {
        const int e = tid & 63, tt = tid >> 6;
        const int t = blk * 2 + tt;
        const float am2 = pm[tt * 128 + e] + pm[tt * 128 + 64 + e];
        const float an2 = pn[tt * 128 + e] + pn[tt * 128 + 64 + e];
        const float sp = fmaxf(an2, 0.f) + log1pf(expf(-fabsf(an2)));
        pm[tt * 128 + e] = am2 + noise[(size_t)t * 64 + e] * sp;
    }
    __syncthreads();

    if (tid < 2) {
        const float* h = pm + tid * 128;
        float b0 = -INFINITY, b1 = -INFINITY;
        int i0 = 0, i1 = 0;
        for (int i = 0; i < N_EXPERTS; ++i) {
            const float v = h[i];
            if (v > b0)      { b1 = b0; i1 = i0; b0 = v; i0 = i; }  // strict >: stable ties
            else if (v > b1) { b1 = v; i1 = i; }
        }
        const float z   = expf(b1 - b0);
        const float inv = 1.f / (1.f + z);
        const int t = blk * 2 + tid;
        esc[t * 2 + 0] = inv;
        esc[t * 2 + 1] = z * inv;
        const int p0 = atomicAdd(&counts[i0], 1);
        if (p0 < LIST_CAP) lists[i0 * LIST_CAP + p0] = t * 2 + 0;
        const int p1 = atomicAdd(&counts[i1], 1);
        if (p1 < LIST_CAP) lists[i1 * LIST_CAP + p1] = t * 2 + 1;
    }
}

// ---------------------------------------------------------------------------
// Fused expert FFN, round 7: K-SPLIT ACROSS WAVES — every weight byte read
// exactly once per block-chunk (was 3x duplicated; R6 was L2/LLC-BW bound).
// grid (64 experts, NGRP) = 256 blocks (1/CU), 1024 threads = 16 waves.
// Phase 1: wave (cq=wave&3, kq=wave>>2) owns W1[kq*128:+128, cq*64:+64];
//   each thread holds 12 token-accumulators (float4 of cols), K-partials
//   reduced shfl_xor(16,32) within wave, then across the 4 kq-waves via
//   disjoint LDS psum buffers + a reduce pass (bias+ReLU fused).
// Phase 2: wave (oct=wave&7, kh=wave>>3) owns W2[kh*128:+128, oct*64:+64];
//   2 kh-partials combined in epilogue (bias+score+atomicAdd fused).
// ---------------------------------------------------------------------------
__global__ __launch_bounds__(1024, 4) void expert_kernel(
    const float* __restrict__ x,
    const float* __restrict__ w1s, const float* __restrict__ b1s,
    const float* __restrict__ w2s, const float* __restrict__ b2s,
    const int* __restrict__ counts, const int* __restrict__ lists,
    const float* __restrict__ esc, float* __restrict__ out)
{
    __shared__ __align__(16) float xs[T_GRP * XPAD];        // 25.0 KB
    __shared__ __align__(16) float vsm[T_GRP * VPAD];       // 12.5 KB
    __shared__ __align__(16) float psum[4 * T_GRP * VPAD];  // 49.9 KB (ph2: 2*T_GRP*P2PAD fits)
    __shared__ int   slotIds[T_GRP];
    __shared__ float escv[T_GRP];

    const int e  = blockIdx.x;
    const int g  = blockIdx.y;
    const int ne = min(counts[e], LIST_CAP);
    const int tid  = threadIdx.x;
    const int wave = tid >> 6, lane = tid & 63;
    const int c4 = lane & 15;          // float4-col within 16-col group
    const int rg = lane >> 4;          // row-group 0..3 (4 consecutive K-rows)

    // phase-1 wave roles: 4 col-quarters x 4 K-quarters
    const int cq   = wave & 3,  kq = wave >> 2;
    const int col1 = cq * 16 + c4;     // float4 col in [0,64) of 256 hidden
    const int k1   = kq * 128 + rg * 4;
    // phase-2 wave roles: 8 col-octants x 2 K-halves
    const int oct  = wave & 7,  kh = wave >> 3;
    const int col2 = oct * 16 + c4;    // float4 col in [0,128) of 512 out
    const int k2   = kh * 128 + rg * 4;

    const float4* w1v = (const float4*)(w1s + (size_t)e * IN_W * BLOCK_H);
    const float4* w2v = (const float4*)(w2s + (size_t)e * BLOCK_H * OUT_W);
    const float4* b1v = (const float4*)(b1s + (size_t)e * BLOCK_H);
    const float4* b2v = (const float4*)(b2s + (size_t)e * OUT_W);
    const float4* x4  = (const float4*)x;

    for (int base = g * T_GRP; base < ne; base += NGRP * T_GRP) {
        const int nTok = min(T_GRP, ne - base);
        if (tid < T_GRP) {
            const int s = (tid < nTok) ? lists[e * LIST_CAP + base + tid] : 0;
            slotIds[tid] = s;
            escv[tid]    = esc[s];
        }
        __syncthreads();

        // stage token rows (zero-pad missing)
        for (int idx = tid; idx < T_GRP * 128; idx += 1024) {
            const int t = idx >> 7, q = idx & 127;
            float4 v = make_float4(0.f, 0.f, 0.f, 0.f);
            if (t < nTok) v = x4[(size_t)(slotIds[t] >> 1) * 128 + q];
            *(float4*)&xs[t * XPAD + q * 4] = v;
        }
        __syncthreads();

        // ---- phase 1: psum[kq] = x @ W1-tile (12 tokens/thread) ----
        {
            float4 acc[T_GRP];
            #pragma unroll
            for (int t = 0; t < T_GRP; ++t) acc[t] = make_float4(0.f,0.f,0.f,0.f);
            const float4* wp = w1v + (size_t)k1 * 64 + col1;
            float4 wb[4];
            #pragma unroll
            for (int k = 0; k < 4; ++k) wb[k] = wp[(size_t)k * 64];
            for (int i = 0; i < 128; i += 16) {
                float4 wc[4];
                #pragma unroll
                for (int k = 0; k < 4; ++k) wc[k] = wb[k];
                if (i + 16 < 128) {
                    #pragma unroll
                    for (int k = 0; k < 4; ++k)
                        wb[k] = wp[(size_t)(i + 16 + k) * 64];
                }
                #pragma unroll
                for (int t = 0; t < T_GRP; ++t) {
                    const float4 xv = *(const float4*)&xs[t * XPAD + k1 + i];
                    fma4(acc[t], xv.x, wc[0]);
                    fma4(acc[t], xv.y, wc[1]);
                    fma4(acc[t], xv.z, wc[2]);
                    fma4(acc[t], xv.w, wc[3]);
                }
            }
            #pragma unroll
            for (int m = 16; m <= 32; m <<= 1) {
                #pragma unroll
                for (int t = 0; t < T_GRP; ++t) {
                    acc[t].x += __shfl_xor(acc[t].x, m);
                    acc[t].y += __shfl_xor(acc[t].y, m);
                    acc[t].z += __shfl_xor(acc[t].z, m);
                    acc[t].w += __shfl_xor(acc[t].w, m);
                }
            }
            if (lane < 16) {
                #pragma unroll
                for (int t = 0; t < T_GRP; ++t)
                    *(float4*)&psum[(kq * T_GRP + t) * VPAD + col1 * 4] = acc[t];
            }
        }
        __syncthreads();

        // ---- reduce kq-partials, fuse bias + ReLU -> vsm ----
        if (tid < T_GRP * 64) {
            const int t = tid >> 6, c = tid & 63;
            const float4 s0 = *(const float4*)&psum[(0 * T_GRP + t) * VPAD + c * 4];
            const float4 s1 = *(const float4*)&psum[(1 * T_GRP + t) * VPAD + c * 4];
            const float4 s2 = *(const float4*)&psum[(2 * T_GRP + t) * VPAD + c * 4];
            const float4 s3 = *(const float4*)&psum[(3 * T_GRP + t) * VPAD + c * 4];
            const float4 bb = b1v[c];
            float4 r;
            r.x = fmaxf(s0.x + s1.x + s2.x + s3.x + bb.x, 0.f);
            r.y = fmaxf(s0.y + s1.y + s2.y + s3.y + bb.y, 0.f);
            r.z = fmaxf(s0.z + s1.z + s2.z + s3.z + bb.z, 0.f);
            r.w = fmaxf(s0.w + s1.w + s2.w + s3.w + bb.w, 0.f);
            *(float4*)&vsm[t * VPAD + c * 4] = r;
        }
        __syncthreads();   // vsm ready; psum free for phase-2 reuse

        // ---- phase 2: psum2[kh] = v @ W2-tile (12 tokens/thread) ----
        {
            float4 acc[T_GRP];
            #pragma unroll
            for (int t = 0; t < T_GRP; ++t) acc[t] = make_float4(0.f,0.f,0.f,0.f);
            const float4* wp2 = w2v + (size_t)k2 * 128 + col2;
            float4 wb[4];
            #pragma unroll
            for (int k = 0; k < 4; ++k) wb[k] = wp2[(size_t)k * 128];
            for (int i = 0; i < 128; i += 16) {
                float4 wc[4];
                #pragma unroll
                for (int k = 0; k < 4; ++k) wc[k] = wb[k];
                if (i + 16 < 128) {
                    #pragma unroll
                    for (int k = 0; k < 4; ++k)
                        wb[k] = wp2[(size_t)(i + 16 + k) * 128];
                }
                #pragma unroll
                for (int t = 0; t < T_GRP; ++t) {
                    const float4 vv = *(const float4*)&vsm[t * VPAD + k2 + i];
                    fma4(acc[t], vv.x, wc[0]);
                    fma4(acc[t], vv.y, wc[1]);
                    fma4(acc[t], vv.z, wc[2]);
                    fma4(acc[t], vv.w, wc[3]);
                }
            }
            #pragma unroll
            for (int m = 16; m <= 32; m <<= 1) {
                #pragma unroll
                for (int t = 0; t < T_GRP; ++t) {
                    acc[t].x += __shfl_xor(acc[t].x, m);
                    acc[t].y += __shfl_xor(acc[t].y, m);
                    acc[t].z += __shfl_xor(acc[t].z, m);
                    acc[t].w += __shfl_xor(acc[t].w, m);
                }
            }
            if (lane < 16) {
                #pragma unroll
                for (int t = 0; t < T_GRP; ++t)
                    *(float4*)&psum[(kh * T_GRP + t) * P2PAD + col2 * 4] = acc[t];
            }
        }
        __syncthreads();

        // ---- epilogue: out += sc * (psum2[0] + psum2[1] + b2) ----
        for (int idx = tid; idx < T_GRP * 128; idx += 1024) {
            const int t = idx >> 7, q = idx & 127;
            if (t < nTok) {
                const float4 s0 = *(const float4*)&psum[(0 * T_GRP + t) * P2PAD + q * 4];
                const float4 s1 = *(const float4*)&psum[(1 * T_GRP + t) * P2PAD + q * 4];
                const float4 bb = b2v[q];
                const float  sc = escv[t];
                float* o = out + (size_t)(slotIds[t] >> 1) * OUT_W + q * 4;
                atomicAdd(o + 0, (s0.x + s1.x + bb.x) * sc);
                atomicAdd(o + 1, (s0.y + s1.y + bb.y) * sc);
                atomicAdd(o + 2, (s0.z + s1.z + bb.z) * sc);
                atomicAdd(o + 3, (s0.w + s1.w + bb.w) * sc);
            }
        }
        __syncthreads();   // buffers reused next chunk (rare: ne > 48)
    }
}

extern "C" void kernel_launch(void* const* d_in, const int* in_sizes, int n_in,
                              void* d_out, int out_size, void* d_ws, size_t ws_size,
                              hipStream_t stream) {
    const float* x      = (const float*)d_in[0];
    const float* noise  = (const float*)d_in[1];
    const float* w1s    = (const float*)d_in[2];
    const float* b1s    = (const float*)d_in[3];
    const float* w2s    = (const float*)d_in[4];
    const float* b2s    = (const float*)d_in[5];
    const float* mixer  = (const float*)d_in[6];
    const float* noisec = (const float*)d_in[7];
    float* out = (float*)d_out;

    // workspace: ~41 KB total (keep far under ws_size; round 2's 2.2 MB
    // layout overran d_ws and corrupted adjacent allocations)
    char* ws = (char*)d_ws;
    int*   counts = (int*)ws;                       ws += 256;
    float* esc    = (float*)ws;                     ws += NSLOTS * sizeof(float);
    int*   lists  = (int*)ws;   /* 64 * 128 ints = 32 KB */

    hipMemsetAsync(d_out, 0, (size_t)out_size * sizeof(float), stream);
    hipMemsetAsync(counts, 0, 256, stream);

    routing_kernel<<<TOKENS / 2, 256, 0, stream>>>(x, noise, mixer, noisec,
                                                   esc, counts, lists);
    expert_kernel<<<dim3(N_EXPERTS, NGRP), 1024, 0, stream>>>(
        x, w1s, b1s, w2s, b2s, counts, lists, esc, out);
}

// Round 8
// 242.831 us; speedup vs baseline: 1.2287x; 1.2287x over previous
//
#include <hip/hip_runtime.h>
#include <math.h>

#define TOKENS    1024
#define IN_W      512
#define BLOCK_H   256
#define OUT_W     512
#define N_EXPERTS 64
#define TOPK      2
#define NSLOTS    (TOKENS * TOPK)
#define LIST_CAP  128     // ne ~ Binom(2048,1/64): mean 32, sigma 5.6
#define T_GRP     8       // tokens per chunk (acc[8] = 32 VGPR: no spill at 512 thr)
#define NGRP      8       // groups per expert -> 512 blocks = 2/CU
#define XPAD      520     // x row stride (floats); 2080 B, 16B-aligned
#define VPAD      260     // v row stride; 1040 B, 16B-aligned
#define OSPAD     516     // out-stage row stride; 2064 B, 16B-aligned

__device__ __forceinline__ void fma4(float4& a, float s, const float4& w) {
    a.x = fmaf(s, w.x, a.x); a.y = fmaf(s, w.y, a.y);
    a.z = fmaf(s, w.z, a.z); a.w = fmaf(s, w.w, a.w);
}

// ---------------------------------------------------------------------------
// Routing + fused compaction (unchanged from round 5; ~3-5 us).
// ---------------------------------------------------------------------------
__global__ __launch_bounds__(256) void routing_kernel(
    const float* __restrict__ x, const float* __restrict__ noise,
    const float* __restrict__ mixer, const float* __restrict__ noisec,
    float* __restrict__ esc, int* __restrict__ counts, int* __restrict__ lists)
{
    __shared__ float xs[2 * 512];
    __shared__ float pm[2 * 2 * 64];
    __shared__ float pn[2 * 2 * 64];
    const int blk  = blockIdx.x;
    const int tid  = threadIdx.x;
    const int wave = tid >> 6, lane = tid & 63;
    const int tq = wave >> 1;
    const int ih = wave & 1;

    ((float4*)xs)[tid] = ((const float4*)x)[(size_t)blk * 256 + tid];
    __syncthreads();

    float am = 0.f, an = 0.f;
    const float* xp = xs + tq * 512 + ih * 256;
    const float* mp = mixer  + (size_t)(ih * 256) * 64 + lane;
    const float* np = noisec + (size_t)(ih * 256) * 64 + lane;
    #pragma unroll 8
    for (int i = 0; i < 256; ++i) {
        const float xv = xp[i];
        am = fmaf(xv, mp[i * 64], am);
        an = fmaf(xv, np[i * 64], an);
    }
    pm[tq * 128 + ih * 64 + lane] = am;
    pn[tq * 128 + ih * 64 + lane] = an;
    __syncthreads();

    if (tid < 128) {
        const int e = tid & 63, tt = tid >> 6;
        const int t = blk * 2 + tt;
        const float am2 = pm[tt * 128 + e] + pm[tt * 128 + 64 + e];
        const float an2 = pn[tt * 128 + e] + pn[tt * 128 + 64 + e];
        const float sp = fmaxf(an2, 0.f) + log1pf(expf(-fabsf(an2)));
        pm[tt * 128 + e] = am2 + noise[(size_t)t * 64 + e] * sp;
    }
    __syncthreads();

    if (tid < 2) {
        const float* h = pm + tid * 128;
        float b0 = -INFINITY, b1 = -INFINITY;
        int i0 = 0, i1 = 0;
        for (int i = 0; i < N_EXPERTS; ++i) {
            const float v = h[i];
            if (v > b0)      { b1 = b0; i1 = i0; b0 = v; i0 = i; }  // strict >: stable ties
            else if (v > b1) { b1 = v; i1 = i; }
        }
        const float z   = expf(b1 - b0);
        const float inv = 1.f / (1.f + z);
        const int t = blk * 2 + tid;
        esc[t * 2 + 0] = inv;
        esc[t * 2 + 1] = z * inv;
        const int p0 = atomicAdd(&counts[i0], 1);
        if (p0 < LIST_CAP) lists[i0 * LIST_CAP + p0] = t * 2 + 0;
        const int p1 = atomicAdd(&counts[i1], 1);
        if (p1 < LIST_CAP) lists[i1 * LIST_CAP + p1] = t * 2 + 1;
    }
}

// ---------------------------------------------------------------------------
// Fused expert FFN, round 8. grid (64, 8) = 512 blocks (2/CU), 512 threads.
// K split ACROSS waves with FULL-ROW weight loads:
//  phase 1: wave w owns W1 rows [w*64, w*64+64); one load instr = 64 lanes x
//    float4 = one full 1 KB row (contiguous, streams like memcpy). Each lane
//    accumulates its 4 cols for all 8 tokens (acc[8] f4 = 32 VGPR).
//    Cross-wave K-partials combined via LDS atomicAdd (ds_add_f32).
//  phase 2: wave (ch=wave&1, kq=wave>>1) owns W2 rows [kq*64,+64), col-half
//    ch (1 KB/row per half). Same accumulate + ds_add into osm.
// W1 read once per block-chunk, W2 twice. No shfl, no big acc arrays, no
// spills (R7's 1024-thread config spilled: WRITE_SIZE 210 MB).
// ---------------------------------------------------------------------------
__global__ __launch_bounds__(512, 4) void expert_kernel(
    const float* __restrict__ x,
    const float* __restrict__ w1s, const float* __restrict__ b1s,
    const float* __restrict__ w2s, const float* __restrict__ b2s,
    const int* __restrict__ counts, const int* __restrict__ lists,
    const float* __restrict__ esc, float* __restrict__ out)
{
    __shared__ __align__(16) float xs [T_GRP * XPAD];    // 16.6 KB
    __shared__ __align__(16) float vsm[T_GRP * VPAD];    //  8.3 KB
    __shared__ __align__(16) float osm[T_GRP * OSPAD];   // 16.5 KB
    __shared__ int   slotIds[T_GRP];
    __shared__ float escv[T_GRP];

    const int e  = blockIdx.x;
    const int g  = blockIdx.y;
    const int ne = min(counts[e], LIST_CAP);
    const int tid  = threadIdx.x;
    const int wave = tid >> 6, lane = tid & 63;

    const float4* w1v = (const float4*)(w1s + (size_t)e * IN_W * BLOCK_H);
    const float4* w2v = (const float4*)(w2s + (size_t)e * BLOCK_H * OUT_W);
    const float*  b1p = b1s + (size_t)e * BLOCK_H;
    const float4* b2v = (const float4*)(b2s + (size_t)e * OUT_W);
    const float4* x4  = (const float4*)x;

    for (int base = g * T_GRP; base < ne; base += NGRP * T_GRP) {
        const int nTok = min(T_GRP, ne - base);
        if (tid < T_GRP) {
            const int s = (tid < nTok) ? lists[e * LIST_CAP + base + tid] : 0;
            slotIds[tid] = s;
            escv[tid]    = esc[s];
        }
        for (int i = tid; i < T_GRP * VPAD; i += 512) vsm[i] = 0.f;
        __syncthreads();

        // stage 8 token rows (zero-pad missing)
        for (int idx = tid; idx < T_GRP * 128; idx += 512) {
            const int t = idx >> 7, q = idx & 127;
            float4 v = make_float4(0.f, 0.f, 0.f, 0.f);
            if (t < nTok) v = x4[(size_t)(slotIds[t] >> 1) * 128 + q];
            *(float4*)&xs[t * XPAD + q * 4] = v;
        }
        __syncthreads();

        // ---- phase 1: vsm += x @ W1[wave's 64 rows]  (full-row loads) ----
        {
            float4 acc[T_GRP];
            #pragma unroll
            for (int t = 0; t < T_GRP; ++t) acc[t] = make_float4(0.f,0.f,0.f,0.f);
            const int r0 = wave * 64;
            const float4* wp = w1v + (size_t)r0 * 64 + lane;   // f4 row stride 64
            float4 wb[4];
            #pragma unroll
            for (int k = 0; k < 4; ++k) wb[k] = wp[(size_t)k * 64];
            for (int i = 0; i < 16; ++i) {
                float4 wc[4];
                #pragma unroll
                for (int k = 0; k < 4; ++k) wc[k] = wb[k];
                if (i < 15) {
                    #pragma unroll
                    for (int k = 0; k < 4; ++k)
                        wb[k] = wp[(size_t)(4 * (i + 1) + k) * 64];
                }
                const int rr = r0 + 4 * i;
                #pragma unroll
                for (int t = 0; t < T_GRP; ++t) {
                    const float4 xv = *(const float4*)&xs[t * XPAD + rr]; // bcast
                    fma4(acc[t], xv.x, wc[0]);
                    fma4(acc[t], xv.y, wc[1]);
                    fma4(acc[t], xv.z, wc[2]);
                    fma4(acc[t], xv.w, wc[3]);
                }
            }
            #pragma unroll
            for (int t = 0; t < T_GRP; ++t) {
                float* p = &vsm[t * VPAD + lane * 4];
                atomicAdd(p + 0, acc[t].x);
                atomicAdd(p + 1, acc[t].y);
                atomicAdd(p + 2, acc[t].z);
                atomicAdd(p + 3, acc[t].w);
            }
        }
        __syncthreads();

        // ---- bias + ReLU on vsm; zero osm ----
        for (int idx = tid; idx < T_GRP * 256; idx += 512) {
            const int t = idx >> 8, c = idx & 255;
            vsm[t * VPAD + c] = fmaxf(vsm[t * VPAD + c] + b1p[c], 0.f);
        }
        for (int i = tid; i < T_GRP * OSPAD; i += 512) osm[i] = 0.f;
        __syncthreads();

        // ---- phase 2: osm += v @ W2[kq's 64 rows, ch's 256-col half] ----
        {
            float4 acc[T_GRP];
            #pragma unroll
            for (int t = 0; t < T_GRP; ++t) acc[t] = make_float4(0.f,0.f,0.f,0.f);
            const int ch = wave & 1, kq = wave >> 1;
            const int h0 = kq * 64;
            const float4* wp2 = w2v + (size_t)h0 * 128 + ch * 64 + lane;
            float4 wb[4];
            #pragma unroll
            for (int k = 0; k < 4; ++k) wb[k] = wp2[(size_t)k * 128];
            for (int i = 0; i < 16; ++i) {
                float4 wc[4];
                #pragma unroll
                for (int k = 0; k < 4; ++k) wc[k] = wb[k];
                if (i < 15) {
                    #pragma unroll
                    for (int k = 0; k < 4; ++k)
                        wb[k] = wp2[(size_t)(4 * (i + 1) + k) * 128];
                }
                const int hh = h0 + 4 * i;
                #pragma unroll
                for (int t = 0; t < T_GRP; ++t) {
                    const float4 vv = *(const float4*)&vsm[t * VPAD + hh]; // bcast
                    fma4(acc[t], vv.x, wc[0]);
                    fma4(acc[t], vv.y, wc[1]);
                    fma4(acc[t], vv.z, wc[2]);
                    fma4(acc[t], vv.w, wc[3]);
                }
            }
            const int cbase = (ch * 64 + lane) * 4;
            #pragma unroll
            for (int t = 0; t < T_GRP; ++t) {
                float* p = &osm[t * OSPAD + cbase];
                atomicAdd(p + 0, acc[t].x);
                atomicAdd(p + 1, acc[t].y);
                atomicAdd(p + 2, acc[t].z);
                atomicAdd(p + 3, acc[t].w);
            }
        }
        __syncthreads();

        // ---- epilogue: out += sc * (osm + b2) ----
        for (int idx = tid; idx < T_GRP * 128; idx += 512) {
            const int t = idx >> 7, q = idx & 127;
            if (t < nTok) {
                const float4 s  = *(const float4*)&osm[t * OSPAD + q * 4];
                const float4 bb = b2v[q];
                const float  sc = escv[t];
                float* o = out + (size_t)(slotIds[t] >> 1) * OUT_W + q * 4;
                atomicAdd(o + 0, (s.x + bb.x) * sc);
                atomicAdd(o + 1, (s.y + bb.y) * sc);
                atomicAdd(o + 2, (s.z + bb.z) * sc);
                atomicAdd(o + 3, (s.w + bb.w) * sc);
            }
        }
        __syncthreads();   // buffers reused next chunk (rare: ne > 64)
    }
}

extern "C" void kernel_launch(void* const* d_in, const int* in_sizes, int n_in,
                              void* d_out, int out_size, void* d_ws, size_t ws_size,
                              hipStream_t stream) {
    const float* x      = (const float*)d_in[0];
    const float* noise  = (const float*)d_in[1];
    const float* w1s    = (const float*)d_in[2];
    const float* b1s    = (const float*)d_in[3];
    const float* w2s    = (const float*)d_in[4];
    const float* b2s    = (const float*)d_in[5];
    const float* mixer  = (const float*)d_in[6];
    const float* noisec = (const float*)d_in[7];
    float* out = (float*)d_out;

    // workspace: ~41 KB total (keep far under ws_size; round 2's 2.2 MB
    // layout overran d_ws and corrupted adjacent allocations)
    char* ws = (char*)d_ws;
    int*   counts = (int*)ws;                       ws += 256;
    float* esc    = (float*)ws;                     ws += NSLOTS * sizeof(float);
    int*   lists  = (int*)ws;   /* 64 * 128 ints = 32 KB */

    hipMemsetAsync(d_out, 0, (size_t)out_size * sizeof(float), stream);
    hipMemsetAsync(counts, 0, 256, stream);

    routing_kernel<<<TOKENS / 2, 256, 0, stream>>>(x, noise, mixer, noisec,
                                                   esc, counts, lists);
    expert_kernel<<<dim3(N_EXPERTS, NGRP), 512, 0, stream>>>(
        x, w1s, b1s, w2s, b2s, counts, lists, esc, out);
}